// Round 1
// baseline (931.245 us; speedup 1.0000x reference)
//
#include <hip/hip_runtime.h>
#include <math.h>

#define NB 8
#define NN 2048
#define SCALE 20.0f   // 1 / 0.05

__device__ __forceinline__ float wave_max(float x) {
#pragma unroll
    for (int off = 32; off >= 1; off >>= 1)
        x = fmaxf(x, __shfl_xor(x, off, 64));
    return x;
}
__device__ __forceinline__ float wave_sum(float x) {
#pragma unroll
    for (int off = 32; off >= 1; off >>= 1)
        x += __shfl_xor(x, off, 64);
    return x;
}

// u[row] = LSE_c(A[row,c]*SCALE - v[c]).  One wave per row, 4 rows per block.
__global__ __launch_bounds__(256) void row_lse(const float* __restrict__ A,
                                               const float* __restrict__ v,
                                               float* __restrict__ u) {
    const int wid  = threadIdx.x >> 6;
    const int lane = threadIdx.x & 63;
    const int row  = blockIdx.x * 4 + wid;       // 0 .. NB*NN-1
    const int b    = row >> 11;                  // row / NN
    const float4* a4 = (const float4*)(A + (size_t)row * NN);
    const float4* v4 = (const float4*)(v + (size_t)b * NN);

    float x[32];
#pragma unroll
    for (int k = 0; k < 8; ++k) {
        float4 a  = a4[lane + (k << 6)];
        float4 vv = v4[lane + (k << 6)];
        x[4 * k + 0] = a.x * SCALE - vv.x;
        x[4 * k + 1] = a.y * SCALE - vv.y;
        x[4 * k + 2] = a.z * SCALE - vv.z;
        x[4 * k + 3] = a.w * SCALE - vv.w;
    }
    float m = -INFINITY;
#pragma unroll
    for (int i = 0; i < 32; ++i) m = fmaxf(m, x[i]);
    m = wave_max(m);
    float s = 0.f;
#pragma unroll
    for (int i = 0; i < 32; ++i) s += __expf(x[i] - m);
    s = wave_sum(s);
    if (lane == 0) u[row] = m + __logf(s);
}

// v[col] = LSE_r(A[r,col]*SCALE - u[r]).  32-col tiles, 8 row-groups, online LSE.
__global__ __launch_bounds__(256) void col_lse(const float* __restrict__ A,
                                               const float* __restrict__ u,
                                               float* __restrict__ v) {
    const int b    = blockIdx.x >> 6;            // 64 tiles per matrix
    const int tile = blockIdx.x & 63;
    const int ci   = threadIdx.x & 31;
    const int rg   = threadIdx.x >> 5;           // 0..7
    const int col  = (tile << 5) + ci;
    const float* Ab = A + (size_t)b * NN * NN;
    const float* ub = u + b * NN;

    float m0 = -INFINITY, s0 = 0.f;
    float m1 = -INFINITY, s1 = 0.f;
    for (int r = rg; r < NN; r += 16) {
        float x0 = Ab[(size_t)r * NN + col] * SCALE - ub[r];
        float x1 = Ab[(size_t)(r + 8) * NN + col] * SCALE - ub[r + 8];
        float nm0 = fmaxf(m0, x0);
        s0 = s0 * __expf(m0 - nm0) + __expf(x0 - nm0);
        m0 = nm0;
        float nm1 = fmaxf(m1, x1);
        s1 = s1 * __expf(m1 - nm1) + __expf(x1 - nm1);
        m1 = nm1;
    }
    float m = fmaxf(m0, m1);
    float s = s0 * __expf(m0 - m) + s1 * __expf(m1 - m);

    __shared__ float sm[8][33];
    __shared__ float ss[8][33];
    sm[rg][ci] = m;
    ss[rg][ci] = s;
    __syncthreads();
    if (threadIdx.x < 32) {
        const int c = threadIdx.x;
        float M = sm[0][c], S = ss[0][c];
#pragma unroll
        for (int g = 1; g < 8; ++g) {
            float mg = sm[g][c], sg = ss[g][c];
            float nM = fmaxf(M, mg);
            S = S * __expf(M - nM) + sg * __expf(mg - nM);
            M = nM;
        }
        v[b * NN + (tile << 5) + c] = M + __logf(S);
    }
}

// out = exp(A*SCALE - u[row] - v[col]), float4 in/out.
__global__ __launch_bounds__(256) void final_exp(const float* __restrict__ A,
                                                 const float* __restrict__ u,
                                                 const float* __restrict__ v,
                                                 float* __restrict__ out) {
    const int i4    = blockIdx.x * 256 + threadIdx.x;  // float4 index
    const int rglob = i4 >> 9;                         // 512 float4 per row
    const int c4    = i4 & 511;
    const int b     = rglob >> 11;
    const float uu  = u[rglob];
    float4 a  = ((const float4*)A)[i4];
    float4 vv = ((const float4*)(v + (size_t)b * NN))[c4];
    float4 o;
    o.x = __expf(a.x * SCALE - uu - vv.x);
    o.y = __expf(a.y * SCALE - uu - vv.y);
    o.z = __expf(a.z * SCALE - uu - vv.z);
    o.w = __expf(a.w * SCALE - uu - vv.w);
    ((float4*)out)[i4] = o;
}

extern "C" void kernel_launch(void* const* d_in, const int* in_sizes, int n_in,
                              void* d_out, int out_size, void* d_ws, size_t ws_size,
                              hipStream_t stream) {
    const float* A = (const float*)d_in[0];
    float* out = (float*)d_out;
    float* u = (float*)d_ws;                 // NB*NN floats
    float* v = u + NB * NN;                  // NB*NN floats

    // v_0 = 0 (ws is poisoned with 0xAA before every launch)
    hipMemsetAsync(v, 0, NB * NN * sizeof(float), stream);

    for (int it = 0; it < 10; ++it) {
        row_lse<<<NB * NN / 4, 256, 0, stream>>>(A, v, u);
        col_lse<<<NB * (NN / 32), 256, 0, stream>>>(A, u, v);
    }
    final_exp<<<NB * NN * NN / 1024, 256, 0, stream>>>(A, u, v, out);
}

// Round 2
// 539.297 us; speedup vs baseline: 1.7268x; 1.7268x over previous
//
#include <hip/hip_runtime.h>
#include <math.h>

#define NB 8
#define NN 2048
#define SCALE 20.0f   // 1 / 0.05
#define RPW 8                // rows per wave in fused pass
#define CH  (NN / RPW)       // 256 partial chunks per matrix

__device__ __forceinline__ float wave_max(float x) {
#pragma unroll
    for (int off = 32; off >= 1; off >>= 1)
        x = fmaxf(x, __shfl_xor(x, off, 64));
    return x;
}
__device__ __forceinline__ float wave_sum(float x) {
#pragma unroll
    for (int off = 32; off >= 1; off >>= 1)
        x += __shfl_xor(x, off, 64);
    return x;
}

// ---------------- fused path ----------------
// One wave owns RPW rows. For each row: u[row] = LSE_c(A*20 - v).
// Column partials: s[c] += exp(A*20 - v[c] - u[row]) = e[c]/S  (arg <= 0, no
// max tracking needed). Per-wave partials written to ps[b][chunk][col].
__global__ __launch_bounds__(256) void fused_iter(const float* __restrict__ A,
                                                  const float* __restrict__ v,
                                                  float* __restrict__ u,
                                                  float* __restrict__ ps) {
    const int wid   = threadIdx.x >> 6;
    const int lane  = threadIdx.x & 63;
    const int wg    = blockIdx.x * 4 + wid;      // 0 .. NB*CH-1
    const int b     = wg / CH;
    const int chunk = wg % CH;
    const int row0  = chunk * RPW;
    const float4* v4 = (const float4*)(v + (size_t)b * NN);

    float s[32];
#pragma unroll
    for (int i = 0; i < 32; ++i) s[i] = 0.f;

#pragma unroll 1
    for (int r = 0; r < RPW; ++r) {
        const float4* a4 = (const float4*)(A + ((size_t)b * NN + row0 + r) * NN);
        float e[32];
        float m = -INFINITY;
#pragma unroll
        for (int k = 0; k < 8; ++k) {
            float4 a  = a4[lane + (k << 6)];
            float4 vv = v4[lane + (k << 6)];
            e[4 * k + 0] = fmaf(a.x, SCALE, -vv.x);
            e[4 * k + 1] = fmaf(a.y, SCALE, -vv.y);
            e[4 * k + 2] = fmaf(a.z, SCALE, -vv.z);
            e[4 * k + 3] = fmaf(a.w, SCALE, -vv.w);
        }
#pragma unroll
        for (int i = 0; i < 32; ++i) m = fmaxf(m, e[i]);
        m = wave_max(m);
        float ls = 0.f;
#pragma unroll
        for (int i = 0; i < 32; ++i) { e[i] = __expf(e[i] - m); ls += e[i]; }
        float S = wave_sum(ls);
        if (lane == 0) u[b * NN + row0 + r] = m + __logf(S);
        float rS = __builtin_amdgcn_rcpf(S);
#pragma unroll
        for (int i = 0; i < 32; ++i) s[i] = fmaf(e[i], rS, s[i]);
    }

    float4* pbase = (float4*)(ps + (size_t)wg * NN);
#pragma unroll
    for (int k = 0; k < 8; ++k)
        pbase[lane + (k << 6)] =
            make_float4(s[4 * k], s[4 * k + 1], s[4 * k + 2], s[4 * k + 3]);
}

// v[c] += log( sum over CH chunks of ps[b][chunk][c] ).
// Block covers 64 cols; 4 thread-groups each sum CH/4 chunks; LDS combine.
__global__ __launch_bounds__(256) void combine(const float* __restrict__ ps,
                                               float* __restrict__ v) {
    const int colg = threadIdx.x & 63;
    const int grp  = threadIdx.x >> 6;           // 0..3
    const int gcol = blockIdx.x * 64 + colg;     // 0 .. NB*NN-1
    const int b    = gcol >> 11;
    const int col  = gcol & (NN - 1);
    const float* pb = ps + (size_t)b * CH * NN + col + (size_t)grp * (CH / 4) * NN;

    float s0 = 0.f, s1 = 0.f, s2 = 0.f, s3 = 0.f;
#pragma unroll 4
    for (int i = 0; i < CH / 4; i += 4) {
        s0 += pb[(size_t)(i + 0) * NN];
        s1 += pb[(size_t)(i + 1) * NN];
        s2 += pb[(size_t)(i + 2) * NN];
        s3 += pb[(size_t)(i + 3) * NN];
    }
    __shared__ float sm[4][64];
    sm[grp][colg] = (s0 + s1) + (s2 + s3);
    __syncthreads();
    if (threadIdx.x < 64) {
        float t = (sm[0][colg] + sm[1][colg]) + (sm[2][colg] + sm[3][colg]);
        v[gcol] += __logf(t);
    }
}

// ---------------- fallback path (round-1 kernels) ----------------
__global__ __launch_bounds__(256) void row_lse(const float* __restrict__ A,
                                               const float* __restrict__ v,
                                               float* __restrict__ u) {
    const int wid  = threadIdx.x >> 6;
    const int lane = threadIdx.x & 63;
    const int row  = blockIdx.x * 4 + wid;
    const int b    = row >> 11;
    const float4* a4 = (const float4*)(A + (size_t)row * NN);
    const float4* v4 = (const float4*)(v + (size_t)b * NN);
    float x[32];
#pragma unroll
    for (int k = 0; k < 8; ++k) {
        float4 a  = a4[lane + (k << 6)];
        float4 vv = v4[lane + (k << 6)];
        x[4 * k + 0] = fmaf(a.x, SCALE, -vv.x);
        x[4 * k + 1] = fmaf(a.y, SCALE, -vv.y);
        x[4 * k + 2] = fmaf(a.z, SCALE, -vv.z);
        x[4 * k + 3] = fmaf(a.w, SCALE, -vv.w);
    }
    float m = -INFINITY;
#pragma unroll
    for (int i = 0; i < 32; ++i) m = fmaxf(m, x[i]);
    m = wave_max(m);
    float s = 0.f;
#pragma unroll
    for (int i = 0; i < 32; ++i) s += __expf(x[i] - m);
    s = wave_sum(s);
    if (lane == 0) u[row] = m + __logf(s);
}

__global__ __launch_bounds__(256) void col_lse(const float* __restrict__ A,
                                               const float* __restrict__ u,
                                               float* __restrict__ v) {
    const int b    = blockIdx.x >> 6;
    const int tile = blockIdx.x & 63;
    const int ci   = threadIdx.x & 31;
    const int rg   = threadIdx.x >> 5;
    const int col  = (tile << 5) + ci;
    const float* Ab = A + (size_t)b * NN * NN;
    const float* ub = u + b * NN;
    float m0 = -INFINITY, s0 = 0.f, m1 = -INFINITY, s1 = 0.f;
    for (int r = rg; r < NN; r += 16) {
        float x0 = fmaf(Ab[(size_t)r * NN + col], SCALE, -ub[r]);
        float x1 = fmaf(Ab[(size_t)(r + 8) * NN + col], SCALE, -ub[r + 8]);
        float nm0 = fmaxf(m0, x0);
        s0 = s0 * __expf(m0 - nm0) + __expf(x0 - nm0); m0 = nm0;
        float nm1 = fmaxf(m1, x1);
        s1 = s1 * __expf(m1 - nm1) + __expf(x1 - nm1); m1 = nm1;
    }
    float m = fmaxf(m0, m1);
    float s = s0 * __expf(m0 - m) + s1 * __expf(m1 - m);
    __shared__ float sm[8][33];
    __shared__ float ss[8][33];
    sm[rg][ci] = m; ss[rg][ci] = s;
    __syncthreads();
    if (threadIdx.x < 32) {
        const int c = threadIdx.x;
        float M = sm[0][c], S = ss[0][c];
#pragma unroll
        for (int g = 1; g < 8; ++g) {
            float mg = sm[g][c], sg = ss[g][c];
            float nM = fmaxf(M, mg);
            S = S * __expf(M - nM) + sg * __expf(mg - nM);
            M = nM;
        }
        v[b * NN + (tile << 5) + c] = M + __logf(S);
    }
}

// ---------------- final ----------------
__global__ __launch_bounds__(256) void final_exp(const float* __restrict__ A,
                                                 const float* __restrict__ u,
                                                 const float* __restrict__ v,
                                                 float* __restrict__ out) {
    const int i4    = blockIdx.x * 256 + threadIdx.x;
    const int rglob = i4 >> 9;
    const int c4    = i4 & 511;
    const int b     = rglob >> 11;
    const float uu  = u[rglob];
    float4 a  = ((const float4*)A)[i4];
    float4 vv = ((const float4*)(v + (size_t)b * NN))[c4];
    float4 o;
    o.x = __expf(fmaf(a.x, SCALE, -uu) - vv.x);
    o.y = __expf(fmaf(a.y, SCALE, -uu) - vv.y);
    o.z = __expf(fmaf(a.z, SCALE, -uu) - vv.z);
    o.w = __expf(fmaf(a.w, SCALE, -uu) - vv.w);
    ((float4*)out)[i4] = o;
}

extern "C" void kernel_launch(void* const* d_in, const int* in_sizes, int n_in,
                              void* d_out, int out_size, void* d_ws, size_t ws_size,
                              hipStream_t stream) {
    const float* A = (const float*)d_in[0];
    float* out = (float*)d_out;
    float* u  = (float*)d_ws;                 // NB*NN floats
    float* v  = u + NB * NN;                  // NB*NN floats
    float* ps = v + NB * NN;                  // NB*CH*NN floats (fused path)

    const size_t need = ((size_t)2 * NB * NN + (size_t)NB * CH * NN) * sizeof(float);

    hipMemsetAsync(v, 0, NB * NN * sizeof(float), stream);

    if (ws_size >= need) {
        for (int it = 0; it < 10; ++it) {
            fused_iter<<<NB * CH / 4, 256, 0, stream>>>(A, v, u, ps);
            combine<<<NB * NN / 64, 256, 0, stream>>>(ps, v);
        }
    } else {
        for (int it = 0; it < 10; ++it) {
            row_lse<<<NB * NN / 4, 256, 0, stream>>>(A, v, u);
            col_lse<<<NB * (NN / 32), 256, 0, stream>>>(A, u, v);
        }
    }
    final_exp<<<NB * NN * NN / 1024, 256, 0, stream>>>(A, u, v, out);
}